// Round 5
// baseline (238.367 us; speedup 1.0000x reference)
//
#include <hip/hip_runtime.h>

// Problem constants (fixed by setup_inputs)
constexpr int B_  = 8;
constexpr int NI  = 4096;
constexpr int NT  = 512;
constexpr int CD  = 1024;

constexpr int BM   = 32;        // img rows per block
constexpr int BK   = 32;        // K per chunk = one mfma_16x16x32 K-step
constexpr int NCH  = CD / BK;   // 32 chunks
constexpr int MAXC = 512;       // candidate list capacity per block
constexpr float DELTA = 0.02f;  // filter margin (~15-20 sigma of fp16 error; mean top-2 gap ~0.32)

typedef __attribute__((ext_vector_type(4))) float    f32x4;
typedef __attribute__((ext_vector_type(8))) _Float16 f16x8;

// workspace layout
constexpr size_t WS_NORM_B = 16384;                        // inv_norm (4096 f32)
constexpr size_t WSB_BYTES = (size_t)B_ * NT * CD * 2;     // 8 MB  fp16 text, chunk-major
constexpr size_t WSA_BYTES = (size_t)B_ * NI * CD * 2;     // 64 MB fp16 img,  chunk-major
constexpr size_t NEED_B    = WS_NORM_B + WSB_BYTES;
constexpr size_t NEED_AB   = NEED_B + WSA_BYTES;

// Kernel 1: inv text norms (bit-identical reduce to R1 — refine replicates R1
// values which matched np argmax exactly) + optional fp16 text panel in
// chunk-major layout wsB[b][kc][t][32].
template<bool PRE>
__global__ __launch_bounds__(256) void prep_text_kernel(const float* __restrict__ text,
                                                        float* __restrict__ inv_norm,
                                                        _Float16* __restrict__ wsB) {
    int row  = blockIdx.x * 4 + (threadIdx.x >> 6);
    int lane = threadIdx.x & 63;
    const float* p = text + (size_t)row * CD;
    float s = 0.f;
#pragma unroll
    for (int it = 0; it < 4; ++it) {
        int k = (lane + it * 64) * 4;
        float4 v = *reinterpret_cast<const float4*>(p + k);
        s = fmaf(v.x, v.x, s); s = fmaf(v.y, v.y, s);
        s = fmaf(v.z, v.z, s); s = fmaf(v.w, v.w, s);
    }
#pragma unroll
    for (int off = 32; off > 0; off >>= 1) s += __shfl_xor(s, off);
    float inv = 1.f / fmaxf(sqrtf(s), 1e-12f);
    if (lane == 0) inv_norm[row] = inv;

    if (PRE) {
        // lane l owns elems k = l*16 .. l*16+15 -> chunk kc = l>>1, half = l&1
        int b = row >> 9, t = row & 511;
        int kc = lane >> 1, half = lane & 1;
        _Float16* dst = wsB + (((size_t)b * 32 + kc) * 512 + t) * 32 + half * 16;
        const float* src = p + lane * 16;
        f16x8 h0, h1;
#pragma unroll
        for (int j = 0; j < 2; ++j) {
            float4 v = *reinterpret_cast<const float4*>(src + j * 4);
            h0[j * 4 + 0] = (_Float16)(v.x * inv); h0[j * 4 + 1] = (_Float16)(v.y * inv);
            h0[j * 4 + 2] = (_Float16)(v.z * inv); h0[j * 4 + 3] = (_Float16)(v.w * inv);
        }
#pragma unroll
        for (int j = 0; j < 2; ++j) {
            float4 v = *reinterpret_cast<const float4*>(src + 8 + j * 4);
            h1[j * 4 + 0] = (_Float16)(v.x * inv); h1[j * 4 + 1] = (_Float16)(v.y * inv);
            h1[j * 4 + 2] = (_Float16)(v.z * inv); h1[j * 4 + 3] = (_Float16)(v.w * inv);
        }
        *reinterpret_cast<f16x8*>(dst)     = h0;
        *reinterpret_cast<f16x8*>(dst + 8) = h1;
    }
}

// Kernel 1b: img -> fp16 chunk-major wsA[b][kc][row][32]. One wave per row,
// fully coalesced 4-KB row reads; 64-B clustered writes.
__global__ __launch_bounds__(512) void prep_img_kernel(const float* __restrict__ img,
                                                       _Float16* __restrict__ wsA) {
    int grow = blockIdx.x * 8 + (threadIdx.x >> 6);   // global img row
    int l    = threadIdx.x & 63;
    int b    = grow >> 12, row = grow & 4095;
    const float* src = img + (size_t)grow * CD + l * 16;
    f16x8 h0, h1;
#pragma unroll
    for (int j = 0; j < 2; ++j) {
        float4 v = *reinterpret_cast<const float4*>(src + j * 4);
        h0[j * 4 + 0] = (_Float16)v.x; h0[j * 4 + 1] = (_Float16)v.y;
        h0[j * 4 + 2] = (_Float16)v.z; h0[j * 4 + 3] = (_Float16)v.w;
    }
#pragma unroll
    for (int j = 0; j < 2; ++j) {
        float4 v = *reinterpret_cast<const float4*>(src + 8 + j * 4);
        h1[j * 4 + 0] = (_Float16)v.x; h1[j * 4 + 1] = (_Float16)v.y;
        h1[j * 4 + 2] = (_Float16)v.z; h1[j * 4 + 3] = (_Float16)v.w;
    }
    _Float16* dst = wsA + (((size_t)b * 32 + (l >> 1)) * 4096 + row) * 32 + (l & 1) * 16;
    *reinterpret_cast<f16x8*>(dst)     = h0;
    *reinterpret_cast<f16x8*>(dst + 8) = h1;
}

// Kernel 2: fp16 MFMA approx sim-GEMM (coalesced chunk-major operands, no
// barriers in K loop, 4-deep A prefetch) + candidate filter + exact fp32
// refine + gather. 256 threads = 4 waves; wave wn owns 32 rows x 128 texts.
// MODE 2: A&B from ws (fp16). MODE 1: B from ws, A from img fp32. MODE 0: raw.
template<int MODE>
__global__ __launch_bounds__(256, 3) void align_kernel(const float* __restrict__ img,
                                                       const float* __restrict__ text,
                                                       const float* __restrict__ inv_norm,
                                                       const _Float16* __restrict__ wsA,
                                                       const _Float16* __restrict__ wsB,
                                                       float* __restrict__ out) {
    __shared__ float pval[4 * BM];
    __shared__ int   pidx[4 * BM];
    __shared__ float sval[BM];
    __shared__ int   sidx[BM];
    __shared__ int   rowcnt[BM];
    __shared__ unsigned long long keys[BM];
    __shared__ int   cand[MAXC];
    __shared__ int   cnt;

    const int tid = threadIdx.x;
    const int l   = tid & 63;
    const int wn  = tid >> 6;      // 0..3 : 128-text slice
    const int q   = l >> 4;        // quarter-wave -> k-slice q*8
    const int ln  = l & 15;

    // XCD swizzle: blockIdx%8 ~ XCD id -> per-XCD L2 holds one batch's panels
    const int b    = blockIdx.x & 7;
    const int row0 = (blockIdx.x >> 3) * BM;

    const float* imgBase  = img  + ((size_t)b * NI + row0) * CD;
    const float* textBase = text + (size_t)b * NT * CD;

    constexpr int DEPTH = (MODE == 2) ? 4 : 2;

    // ---- operand bases ----
    // A (MODE2): wsA + b*32*4096*32 + (row0+mi*16+ln)*32 + q*8 ; chunk stride 131072 halfs
    const _Float16* aBase = wsA + (size_t)b * ((size_t)32 * 4096 * 32)
                          + ((size_t)row0 + ln) * 32 + q * 8;
    // A (MODE<2): fp32 img rows
    const float* aPtrF[2];
#pragma unroll
    for (int mi = 0; mi < 2; ++mi)
        aPtrF[mi] = imgBase + (size_t)(mi * 16 + ln) * CD + q * 8;
    // B (MODE>=1): wsB + b*32*512*32 + (wn*128+ln)*32 + q*8 ; chunk stride 16384 halfs
    const _Float16* bBase = wsB + (size_t)b * ((size_t)32 * 512 * 32)
                          + ((size_t)(wn * 128 + ln)) * 32 + q * 8;
    // B (MODE0): fp32 text
    const float* bPtrF[8];
    float invn8[8];
    if (MODE == 0) {
#pragma unroll
        for (int nj = 0; nj < 8; ++nj) {
            int t = wn * 128 + nj * 16 + ln;
            bPtrF[nj] = textBase + (size_t)t * CD + q * 8;
            invn8[nj] = inv_norm[b * NT + t];
        }
    }

    f32x4 acc[2][8];
#pragma unroll
    for (int mi = 0; mi < 2; ++mi)
#pragma unroll
        for (int nj = 0; nj < 8; ++nj) acc[mi][nj] = (f32x4)0.f;

    // ---- prologue: prefetch DEPTH chunks of A ----
    f16x8  af[DEPTH][2];      // MODE2
    float4 ar0[DEPTH][2], ar1[DEPTH][2];  // MODE<2 raw fp32
#pragma unroll
    for (int j = 0; j < DEPTH; ++j) {
#pragma unroll
        for (int mi = 0; mi < 2; ++mi) {
            if (MODE == 2) {
                af[j][mi] = *reinterpret_cast<const f16x8*>(aBase + (size_t)j * 131072 + mi * 512);
            } else {
                ar0[j][mi] = *reinterpret_cast<const float4*>(aPtrF[mi] + j * BK);
                ar1[j][mi] = *reinterpret_cast<const float4*>(aPtrF[mi] + j * BK + 4);
            }
        }
    }

#pragma unroll 1
    for (int kc = 0; kc < NCH; kc += DEPTH) {
#pragma unroll
        for (int j = 0; j < DEPTH; ++j) {
            const int k = kc + j;
            // B loads for chunk k
            f16x8 bf[8];
            if (MODE >= 1) {
#pragma unroll
                for (int nj = 0; nj < 8; ++nj)
                    bf[nj] = *reinterpret_cast<const f16x8*>(bBase + (size_t)k * 16384 + nj * 512);
            } else {
#pragma unroll
                for (int nj = 0; nj < 8; ++nj) {
                    float4 v0 = *reinterpret_cast<const float4*>(bPtrF[nj] + k * BK);
                    float4 v1 = *reinterpret_cast<const float4*>(bPtrF[nj] + k * BK + 4);
                    float sj = invn8[nj];
                    f16x8 t;
                    t[0] = (_Float16)(v0.x * sj); t[1] = (_Float16)(v0.y * sj);
                    t[2] = (_Float16)(v0.z * sj); t[3] = (_Float16)(v0.w * sj);
                    t[4] = (_Float16)(v1.x * sj); t[5] = (_Float16)(v1.y * sj);
                    t[6] = (_Float16)(v1.z * sj); t[7] = (_Float16)(v1.w * sj);
                    bf[nj] = t;
                }
            }
            // A fragments for chunk k
            f16x8 am[2];
            if (MODE == 2) {
                am[0] = af[j][0]; am[1] = af[j][1];
            } else {
#pragma unroll
                for (int mi = 0; mi < 2; ++mi) {
                    f16x8 t;
                    t[0] = (_Float16)ar0[j][mi].x; t[1] = (_Float16)ar0[j][mi].y;
                    t[2] = (_Float16)ar0[j][mi].z; t[3] = (_Float16)ar0[j][mi].w;
                    t[4] = (_Float16)ar1[j][mi].x; t[5] = (_Float16)ar1[j][mi].y;
                    t[6] = (_Float16)ar1[j][mi].z; t[7] = (_Float16)ar1[j][mi].w;
                    am[mi] = t;
                }
            }
            // 16 MFMA
#pragma unroll
            for (int nj = 0; nj < 8; ++nj)
#pragma unroll
                for (int mi = 0; mi < 2; ++mi)
                    acc[mi][nj] = __builtin_amdgcn_mfma_f32_16x16x32_f16(am[mi], bf[nj], acc[mi][nj], 0, 0, 0);
            // prefetch chunk k+DEPTH into slot j (static index)
            if (k + DEPTH < NCH) {
#pragma unroll
                for (int mi = 0; mi < 2; ++mi) {
                    if (MODE == 2) {
                        af[j][mi] = *reinterpret_cast<const f16x8*>(aBase + (size_t)(k + DEPTH) * 131072 + mi * 512);
                    } else {
                        ar0[j][mi] = *reinterpret_cast<const float4*>(aPtrF[mi] + (k + DEPTH) * BK);
                        ar1[j][mi] = *reinterpret_cast<const float4*>(aPtrF[mi] + (k + DEPTH) * BK + 4);
                    }
                }
            }
        }
    }

    // --- approx argmax per row WITH index (first-occurrence tie rule) ---
    // C/D layout: col = ln (text), row = q*4 + r  [m89]
#pragma unroll
    for (int mi = 0; mi < 2; ++mi) {
#pragma unroll
        for (int r = 0; r < 4; ++r) {
            float m  = acc[mi][0][r];
            int   bi = wn * 128 + ln;
#pragma unroll
            for (int nj = 1; nj < 8; ++nj) {
                float v = acc[mi][nj][r];
                int  ci = wn * 128 + nj * 16 + ln;
                if (v > m) { m = v; bi = ci; }
            }
#pragma unroll
            for (int off = 1; off < 16; off <<= 1) {
                float om = __shfl_xor(m, off);
                int   oi = __shfl_xor(bi, off);
                if (om > m || (om == m && oi < bi)) { m = om; bi = oi; }
            }
            if (ln == 0) {
                int rl = mi * 16 + q * 4 + r;
                pval[wn * BM + rl] = m;
                pidx[wn * BM + rl] = bi;
            }
        }
    }
    __syncthreads();

    // --- merge 4 wn-slices (ascending wn = ascending col -> first-occurrence) ---
    if (tid < BM) {
        float bv = pval[tid];
        int   bi = pidx[tid];
#pragma unroll
        for (int ww = 1; ww < 4; ++ww) {
            float v  = pval[ww * BM + tid];
            int   i2 = pidx[ww * BM + tid];
            if (v > bv || (v == bv && i2 < bi)) { bv = v; bi = i2; }
        }
        sval[tid]   = bv;
        sidx[tid]   = bi;    // exact answer if rowcnt==1
        rowcnt[tid] = 0;
        keys[tid]   = 0ull;
    }
    if (tid == 0) cnt = 0;
    __syncthreads();

    // --- candidate collection: all (row,t) with approx >= rowmax - DELTA ---
    {
        float thr[2][4];
#pragma unroll
        for (int mi = 0; mi < 2; ++mi)
#pragma unroll
            for (int r = 0; r < 4; ++r)
                thr[mi][r] = sval[mi * 16 + q * 4 + r] - DELTA;
#pragma unroll
        for (int mi = 0; mi < 2; ++mi)
#pragma unroll
            for (int nj = 0; nj < 8; ++nj)
#pragma unroll
                for (int r = 0; r < 4; ++r) {
                    if (acc[mi][nj][r] >= thr[mi][r]) {
                        int rl = mi * 16 + q * 4 + r;
                        int t  = wn * 128 + nj * 16 + ln;
                        atomicAdd(&rowcnt[rl], 1);
                        int slot = atomicAdd(&cnt, 1);
                        if (slot < MAXC) cand[slot] = (rl << 16) | t;
                    }
                }
    }
    __syncthreads();

    // --- exact fp32 refine, only rows with >=2 candidates.
    // Replicates R1 arithmetic exactly (ascending-k fmaf chain, text elem
    // scaled by inv_norm with one fp32 mul) -> matches np argmax (proven R3/R4).
    {
        int n = cnt < MAXC ? cnt : MAXC;
        for (int c = tid; c < n; c += 256) {
            int rt = cand[c];
            int rl = rt >> 16;
            int t  = rt & 0xFFFF;
            if (rowcnt[rl] < 2) continue;
            const float* ap = imgBase  + (size_t)rl * CD;
            const float* bp = textBase + (size_t)t  * CD;
            float s = inv_norm[b * NT + t];
            float accv = 0.f;
#pragma unroll 2
            for (int k = 0; k < CD; k += 4) {
                float4 av = *reinterpret_cast<const float4*>(ap + k);
                float4 bv = *reinterpret_cast<const float4*>(bp + k);
                accv = fmaf(av.x, bv.x * s, accv);
                accv = fmaf(av.y, bv.y * s, accv);
                accv = fmaf(av.z, bv.z * s, accv);
                accv = fmaf(av.w, bv.w * s, accv);
            }
            unsigned ub = __float_as_uint(accv);
            unsigned su = ub ^ ((unsigned)((int)ub >> 31) | 0x80000000u);
            unsigned long long key =
                ((unsigned long long)su << 32) | (unsigned)(NT - 1 - t);
            atomicMax(&keys[rl], key);
        }
    }
    __syncthreads();

    if (tid < BM && rowcnt[tid] > 1)
        sidx[tid] = NT - 1 - (int)(keys[tid] & 0xFFFFFFFFull);
    __syncthreads();

    // --- gather: wave wn copies rows wn*8 .. wn*8+7, coalesced float4 ---
    float* outBase = out + ((size_t)b * NI + row0) * CD;
#pragma unroll 1
    for (int rr = 0; rr < 8; ++rr) {
        int row = wn * 8 + rr;
        int ti  = sidx[row];
        const float4* src = reinterpret_cast<const float4*>(textBase + (size_t)ti * CD);
        float4*       dst = reinterpret_cast<float4*>(outBase + (size_t)row * CD);
#pragma unroll
        for (int i = 0; i < 4; ++i) dst[l + 64 * i] = src[l + 64 * i];
    }
}

extern "C" void kernel_launch(void* const* d_in, const int* in_sizes, int n_in,
                              void* d_out, int out_size, void* d_ws, size_t ws_size,
                              hipStream_t stream) {
    const float* img  = (const float*)d_in[0];   // [8,4096,1024] fp32
    const float* text = (const float*)d_in[1];   // [8,512,1024] fp32
    float* out      = (float*)d_out;             // [8,4096,1024] fp32
    float* inv_norm = (float*)d_ws;
    _Float16* wsB   = (_Float16*)((char*)d_ws + WS_NORM_B);
    _Float16* wsA   = (_Float16*)((char*)d_ws + NEED_B);

    const int gridAlign = NI / BM * B_;   // 1024
    if (ws_size >= NEED_AB) {
        prep_text_kernel<true><<<dim3(B_ * NT / 4), 256, 0, stream>>>(text, inv_norm, wsB);
        prep_img_kernel<<<dim3(B_ * NI / 8), 512, 0, stream>>>(img, wsA);
        align_kernel<2><<<dim3(gridAlign), 256, 0, stream>>>(img, text, inv_norm, wsA, wsB, out);
    } else if (ws_size >= NEED_B) {
        prep_text_kernel<true><<<dim3(B_ * NT / 4), 256, 0, stream>>>(text, inv_norm, wsB);
        align_kernel<1><<<dim3(gridAlign), 256, 0, stream>>>(img, text, inv_norm, wsB, wsB, out);
    } else {
        prep_text_kernel<false><<<dim3(B_ * NT / 4), 256, 0, stream>>>(text, inv_norm, wsB);
        align_kernel<0><<<dim3(gridAlign), 256, 0, stream>>>(img, text, inv_norm, wsB, wsB, out);
    }
}

// Round 6
// 129.118 us; speedup vs baseline: 1.8461x; 1.8461x over previous
//
#include <hip/hip_runtime.h>

// Problem constants (fixed by setup_inputs)
constexpr int B_  = 8;
constexpr int NI  = 4096;
constexpr int NT  = 512;
constexpr int CD  = 1024;

constexpr int BM   = 64;        // img rows per block
constexpr int BK   = 32;        // K per chunk = one mfma_16x16x32 K-step
constexpr int NCH  = CD / BK;   // 32 chunks
constexpr int MAXC = 256;       // candidate list capacity per block
constexpr float DELTA = 0.02f;  // ~60 sigma of fp16 approx error; mean top-2 gap ~0.28

typedef __attribute__((ext_vector_type(4))) float    f32x4;
typedef __attribute__((ext_vector_type(8))) _Float16 f16x8;

// workspace layout
constexpr size_t WS_NORM_B = 16384;                      // inv_norm (4096 f32)
constexpr size_t WSB_BYTES = (size_t)B_ * NT * CD * 2;   // 8 MB fp16 text, chunk-major
constexpr size_t NEED_B    = WS_NORM_B + WSB_BYTES;

__device__ __forceinline__ void gl_lds16(const void* g, void* l) {
    __builtin_amdgcn_global_load_lds(
        (const __attribute__((address_space(1))) unsigned int*)g,
        (__attribute__((address_space(3))) unsigned int*)l,
        16, 0, 0);
}

// Kernel 1: inv text norms (reduce kept bit-identical to R1 — the refine step
// replicates R1 per-(row,t) fp32 values whose argmax matched np exactly) +
// optional fp16 pre-scaled text in chunk-major layout wsB[b][kc][t][32]
// (= exact LDS slab image for global_load_lds).
template<bool PRE>
__global__ __launch_bounds__(256) void prep_text_kernel(const float* __restrict__ text,
                                                        float* __restrict__ inv_norm,
                                                        _Float16* __restrict__ wsB) {
    int row  = blockIdx.x * 4 + (threadIdx.x >> 6);
    int lane = threadIdx.x & 63;
    const float* p = text + (size_t)row * CD;
    float s = 0.f;
#pragma unroll
    for (int it = 0; it < 4; ++it) {
        int k = (lane + it * 64) * 4;
        float4 v = *reinterpret_cast<const float4*>(p + k);
        s = fmaf(v.x, v.x, s); s = fmaf(v.y, v.y, s);
        s = fmaf(v.z, v.z, s); s = fmaf(v.w, v.w, s);
    }
#pragma unroll
    for (int off = 32; off > 0; off >>= 1) s += __shfl_xor(s, off);
    float inv = 1.f / fmaxf(sqrtf(s), 1e-12f);
    if (lane == 0) inv_norm[row] = inv;

    if (PRE) {
        // lane l owns elems k = l*16 .. l*16+15 -> chunk kc = l>>1, half = l&1
        int b = row >> 9, t = row & 511;
        int kc = lane >> 1, half = lane & 1;
        _Float16* dst = wsB + (((size_t)b * 32 + kc) * 512 + t) * 32 + half * 16;
        const float* src = p + lane * 16;
        f16x8 h0, h1;
#pragma unroll
        for (int j = 0; j < 2; ++j) {
            float4 v = *reinterpret_cast<const float4*>(src + j * 4);
            h0[j * 4 + 0] = (_Float16)(v.x * inv); h0[j * 4 + 1] = (_Float16)(v.y * inv);
            h0[j * 4 + 2] = (_Float16)(v.z * inv); h0[j * 4 + 3] = (_Float16)(v.w * inv);
        }
#pragma unroll
        for (int j = 0; j < 2; ++j) {
            float4 v = *reinterpret_cast<const float4*>(src + 8 + j * 4);
            h1[j * 4 + 0] = (_Float16)(v.x * inv); h1[j * 4 + 1] = (_Float16)(v.y * inv);
            h1[j * 4 + 2] = (_Float16)(v.z * inv); h1[j * 4 + 3] = (_Float16)(v.w * inv);
        }
        *reinterpret_cast<f16x8*>(dst)     = h0;
        *reinterpret_cast<f16x8*>(dst + 8) = h1;
    }
}

// Kernel 2: m97-style LDS double-buffered fp16 MFMA sim-GEMM:
//   B: global_load_lds (16B) from pre-scaled fp16 wsB slab (WS=1) or
//      reg-staged fp32 text + scale + cvt (WS=0 fallback)
//   A: fp32 global -> reg -> cvt fp16 -> ds_write (no prep pass, img read once)
// One barrier per chunk. 256 thr = 4 waves; wave w owns all 64 rows x 128 texts.
// Epilogue: approx argmax + candidate filter + exact fp32 refine + gather.
template<int WS>
__global__ __launch_bounds__(256, 2) void align_kernel(const float* __restrict__ img,
                                                       const float* __restrict__ text,
                                                       const float* __restrict__ inv_norm,
                                                       const _Float16* __restrict__ wsB,
                                                       float* __restrict__ out) {
    __shared__ _Float16 sA[2][BM * BK];   // 8 KB
    __shared__ _Float16 sB[2][NT * BK];   // 64 KB
    __shared__ float pval[4 * BM];
    __shared__ int   pidx[4 * BM];
    __shared__ float sval[BM];
    __shared__ int   sidx[BM];
    __shared__ int   rowcnt[BM];
    __shared__ unsigned long long keys[BM];
    __shared__ int   cand[MAXC];
    __shared__ int   cnt;

    const int tid = threadIdx.x;
    const int l   = tid & 63;
    const int w   = tid >> 6;      // wave = text slice (0..3)
    const int q   = l >> 4;        // quarter-wave -> k-slice q*8
    const int ln  = l & 15;

    const int b    = blockIdx.x & 7;
    const int row0 = (blockIdx.x >> 3) * BM;

    const float* imgBase  = img  + ((size_t)b * NI + row0) * CD;
    const float* textBase = text + (size_t)b * NT * CD;

    // A staging: thread -> (row = tid>>2, k0 = (tid&3)*8); LDS byte off = tid*16
    const int arow = tid >> 2, ak0 = (tid & 3) * 8;
    const float* aSrc = imgBase + (size_t)arow * CD + ak0;

    // B staging (WS): slab for (b,kc) is 512 rows x 64 B, exact LDS image
    const _Float16* bSlab = wsB + (size_t)b * 32 * (NT * BK);

    // B staging (fallback): thread stages text rows tid and tid+256
    float invT0 = 0.f, invT1 = 0.f;
    if (!WS) {
        invT0 = inv_norm[b * NT + tid];
        invT1 = inv_norm[b * NT + tid + 256];
    }

    f32x4 acc[4][8];
#pragma unroll
    for (int mi = 0; mi < 4; ++mi)
#pragma unroll
        for (int nj = 0; nj < 8; ++nj) acc[mi][nj] = (f32x4)0.f;

    // ---- prologue: stage chunk 0 into buf 0 ----
    {
        float4 a0 = *reinterpret_cast<const float4*>(aSrc);
        float4 a1 = *reinterpret_cast<const float4*>(aSrc + 4);
        if (WS) {
#pragma unroll
            for (int i = 0; i < 8; ++i)
                gl_lds16(bSlab + (i * 4 + w) * 512 + l * 8, &sB[0][(i * 4 + w) * 512]);
        } else {
#pragma unroll
            for (int rr = 0; rr < 2; ++rr) {
                int t = tid + rr * 256;
                float sj = rr ? invT1 : invT0;
                const float* bp = textBase + (size_t)t * CD;
#pragma unroll
                for (int j = 0; j < 4; ++j) {
                    float4 v0 = *reinterpret_cast<const float4*>(bp + j * 8);
                    float4 v1 = *reinterpret_cast<const float4*>(bp + j * 8 + 4);
                    f16x8 h;
                    h[0] = (_Float16)(v0.x * sj); h[1] = (_Float16)(v0.y * sj);
                    h[2] = (_Float16)(v0.z * sj); h[3] = (_Float16)(v0.w * sj);
                    h[4] = (_Float16)(v1.x * sj); h[5] = (_Float16)(v1.y * sj);
                    h[6] = (_Float16)(v1.z * sj); h[7] = (_Float16)(v1.w * sj);
                    *reinterpret_cast<f16x8*>(&sB[0][t * 32 + j * 8]) = h;
                }
            }
        }
        f16x8 h;
        h[0] = (_Float16)a0.x; h[1] = (_Float16)a0.y; h[2] = (_Float16)a0.z; h[3] = (_Float16)a0.w;
        h[4] = (_Float16)a1.x; h[5] = (_Float16)a1.y; h[6] = (_Float16)a1.z; h[7] = (_Float16)a1.w;
        *reinterpret_cast<f16x8*>(&sA[0][tid * 8]) = h;
    }
    __syncthreads();

    // ---- main loop: one barrier per chunk, double-buffered ----
    int buf = 0;
#pragma unroll 1
    for (int kc = 0; kc < NCH; ++kc) {
        const int nbuf = buf ^ 1;
        float4 na0, na1;
        const bool more = (kc + 1 < NCH);
        if (more) {
            // issue next A (regs) and next B (gload_lds) -- latency hidden under MFMA
            na0 = *reinterpret_cast<const float4*>(aSrc + (kc + 1) * BK);
            na1 = *reinterpret_cast<const float4*>(aSrc + (kc + 1) * BK + 4);
            if (WS) {
                const _Float16* bs = bSlab + (size_t)(kc + 1) * (NT * BK);
#pragma unroll
                for (int i = 0; i < 8; ++i)
                    gl_lds16(bs + (i * 4 + w) * 512 + l * 8, &sB[nbuf][(i * 4 + w) * 512]);
            }
        }

        // compute chunk kc from buf: 4 A-frags + 8 B-frags, 32 MFMA
        f16x8 af[4];
#pragma unroll
        for (int mi = 0; mi < 4; ++mi)
            af[mi] = *reinterpret_cast<const f16x8*>(&sA[buf][(mi * 16 + ln) * 32 + q * 8]);
#pragma unroll
        for (int nj = 0; nj < 8; ++nj) {
            f16x8 bf = *reinterpret_cast<const f16x8*>(&sB[buf][(w * 128 + nj * 16 + ln) * 32 + q * 8]);
#pragma unroll
            for (int mi = 0; mi < 4; ++mi)
                acc[mi][nj] = __builtin_amdgcn_mfma_f32_16x16x32_f16(af[mi], bf, acc[mi][nj], 0, 0, 0);
        }

        if (more) {
            if (!WS) {
#pragma unroll
                for (int rr = 0; rr < 2; ++rr) {
                    int t = tid + rr * 256;
                    float sj = rr ? invT1 : invT0;
                    const float* bp = textBase + (size_t)t * CD + (kc + 1) * BK;
#pragma unroll
                    for (int j = 0; j < 4; ++j) {
                        float4 v0 = *reinterpret_cast<const float4*>(bp + j * 8);
                        float4 v1 = *reinterpret_cast<const float4*>(bp + j * 8 + 4);
                        f16x8 h;
                        h[0] = (_Float16)(v0.x * sj); h[1] = (_Float16)(v0.y * sj);
                        h[2] = (_Float16)(v0.z * sj); h[3] = (_Float16)(v0.w * sj);
                        h[4] = (_Float16)(v1.x * sj); h[5] = (_Float16)(v1.y * sj);
                        h[6] = (_Float16)(v1.z * sj); h[7] = (_Float16)(v1.w * sj);
                        *reinterpret_cast<f16x8*>(&sB[nbuf][t * 32 + j * 8]) = h;
                    }
                }
            }
            f16x8 h;
            h[0] = (_Float16)na0.x; h[1] = (_Float16)na0.y; h[2] = (_Float16)na0.z; h[3] = (_Float16)na0.w;
            h[4] = (_Float16)na1.x; h[5] = (_Float16)na1.y; h[6] = (_Float16)na1.z; h[7] = (_Float16)na1.w;
            *reinterpret_cast<f16x8*>(&sA[nbuf][tid * 8]) = h;
        }
        __syncthreads();   // publishes nbuf (drains gload_lds + ds_write)
        buf = nbuf;
    }

    // --- approx argmax per row WITH index (first-occurrence tie rule) ---
    // C/D layout: col = ln (text), row = q*4 + r  [m89]
#pragma unroll
    for (int mi = 0; mi < 4; ++mi) {
#pragma unroll
        for (int r = 0; r < 4; ++r) {
            float m  = acc[mi][0][r];
            int   bi = w * 128 + ln;
#pragma unroll
            for (int nj = 1; nj < 8; ++nj) {
                float v = acc[mi][nj][r];
                int  ci = w * 128 + nj * 16 + ln;
                if (v > m) { m = v; bi = ci; }
            }
#pragma unroll
            for (int off = 1; off < 16; off <<= 1) {
                float om = __shfl_xor(m, off);
                int   oi = __shfl_xor(bi, off);
                if (om > m || (om == m && oi < bi)) { m = om; bi = oi; }
            }
            if (ln == 0) {
                int rl = mi * 16 + q * 4 + r;
                pval[w * BM + rl] = m;
                pidx[w * BM + rl] = bi;
            }
        }
    }
    __syncthreads();

    // --- merge 4 slices (ascending w = ascending col -> first-occurrence) ---
    if (tid < BM) {
        float bv = pval[tid];
        int   bi = pidx[tid];
#pragma unroll
        for (int ww = 1; ww < 4; ++ww) {
            float v  = pval[ww * BM + tid];
            int   i2 = pidx[ww * BM + tid];
            if (v > bv || (v == bv && i2 < bi)) { bv = v; bi = i2; }
        }
        sval[tid]   = bv;
        sidx[tid]   = bi;    // exact answer if rowcnt==1
        rowcnt[tid] = 0;
        keys[tid]   = 0ull;
    }
    if (tid == 0) cnt = 0;
    __syncthreads();

    // --- candidate collection: all (row,t) with approx >= rowmax - DELTA ---
    {
        float thr[4][4];
#pragma unroll
        for (int mi = 0; mi < 4; ++mi)
#pragma unroll
            for (int r = 0; r < 4; ++r)
                thr[mi][r] = sval[mi * 16 + q * 4 + r] - DELTA;
#pragma unroll
        for (int mi = 0; mi < 4; ++mi)
#pragma unroll
            for (int nj = 0; nj < 8; ++nj)
#pragma unroll
                for (int r = 0; r < 4; ++r) {
                    if (acc[mi][nj][r] >= thr[mi][r]) {
                        int rl = mi * 16 + q * 4 + r;
                        int t  = w * 128 + nj * 16 + ln;
                        atomicAdd(&rowcnt[rl], 1);
                        int slot = atomicAdd(&cnt, 1);
                        if (slot < MAXC) cand[slot] = (rl << 16) | t;
                    }
                }
    }
    __syncthreads();

    // --- exact fp32 refine, only rows with >=2 candidates.
    // Replicates R1 arithmetic exactly -> matches np argmax (proven R3/R4/R5).
    {
        int n = cnt < MAXC ? cnt : MAXC;
        for (int c = tid; c < n; c += 256) {
            int rt = cand[c];
            int rl = rt >> 16;
            int t  = rt & 0xFFFF;
            if (rowcnt[rl] < 2) continue;
            const float* ap = imgBase  + (size_t)rl * CD;
            const float* bp = textBase + (size_t)t  * CD;
            float s = inv_norm[b * NT + t];
            float accv = 0.f;
#pragma unroll 2
            for (int k = 0; k < CD; k += 4) {
                float4 av = *reinterpret_cast<const float4*>(ap + k);
                float4 bv = *reinterpret_cast<const float4*>(bp + k);
                accv = fmaf(av.x, bv.x * s, accv);
                accv = fmaf(av.y, bv.y * s, accv);
                accv = fmaf(av.z, bv.z * s, accv);
                accv = fmaf(av.w, bv.w * s, accv);
            }
            unsigned ub = __float_as_uint(accv);
            unsigned su = ub ^ ((unsigned)((int)ub >> 31) | 0x80000000u);
            unsigned long long key =
                ((unsigned long long)su << 32) | (unsigned)(NT - 1 - t);
            atomicMax(&keys[rl], key);
        }
    }
    __syncthreads();

    if (tid < BM && rowcnt[tid] > 1)
        sidx[tid] = NT - 1 - (int)(keys[tid] & 0xFFFFFFFFull);
    __syncthreads();

    // --- gather: 256 threads copy each of 64 rows (one float4/thread/row) ---
    float* outBase = out + ((size_t)b * NI + row0) * CD;
#pragma unroll 1
    for (int r = 0; r < BM; ++r) {
        int ti = sidx[r];
        const float4* src = reinterpret_cast<const float4*>(textBase + (size_t)ti * CD);
        float4*       dst = reinterpret_cast<float4*>(outBase + (size_t)r * CD);
        dst[tid] = src[tid];
    }
}

extern "C" void kernel_launch(void* const* d_in, const int* in_sizes, int n_in,
                              void* d_out, int out_size, void* d_ws, size_t ws_size,
                              hipStream_t stream) {
    const float* img  = (const float*)d_in[0];   // [8,4096,1024] fp32
    const float* text = (const float*)d_in[1];   // [8,512,1024] fp32
    float* out      = (float*)d_out;             // [8,4096,1024] fp32
    float* inv_norm = (float*)d_ws;
    _Float16* wsB   = (_Float16*)((char*)d_ws + WS_NORM_B);

    const int gridAlign = NI / BM * B_;   // 512
    if (ws_size >= NEED_B) {
        prep_text_kernel<true><<<dim3(B_ * NT / 4), 256, 0, stream>>>(text, inv_norm, wsB);
        align_kernel<1><<<dim3(gridAlign), 256, 0, stream>>>(img, text, inv_norm, wsB, out);
    } else {
        prep_text_kernel<false><<<dim3(B_ * NT / 4), 256, 0, stream>>>(text, inv_norm, wsB);
        align_kernel<0><<<dim3(gridAlign), 256, 0, stream>>>(img, text, inv_norm, wsB, out);
    }
}

// Round 7
// 124.641 us; speedup vs baseline: 1.9124x; 1.0359x over previous
//
#include <hip/hip_runtime.h>

// Problem constants (fixed by setup_inputs)
constexpr int B_  = 8;
constexpr int NI  = 4096;
constexpr int NT  = 512;
constexpr int CD  = 1024;

constexpr int BM   = 64;        // img rows per block
constexpr int BK   = 32;        // K per chunk = one mfma_16x16x32 K-step
constexpr int NCH  = CD / BK;   // 32 chunks
constexpr int MAXC = 512;       // candidate list capacity per block
constexpr float DELTA = 0.02f;  // ~20 sigma of fp16 approx error; mean top-2 gap ~0.28

typedef __attribute__((ext_vector_type(4))) float    f32x4;
typedef __attribute__((ext_vector_type(4))) _Float16 f16x4;
typedef __attribute__((ext_vector_type(8))) _Float16 f16x8;

// workspace layout
constexpr size_t WS_NORM_B = 16384;                      // inv_norm (4096 f32)
constexpr size_t WSB_BYTES = (size_t)B_ * NT * CD * 2;   // 8 MB fp16 text, chunk-major q-major
constexpr size_t NEED_B    = WS_NORM_B + WSB_BYTES;

__device__ __forceinline__ void gl_lds16(const void* g, void* l) {
    __builtin_amdgcn_global_load_lds(
        (const __attribute__((address_space(1))) unsigned int*)g,
        (__attribute__((address_space(3))) unsigned int*)l,
        16, 0, 0);
}

__device__ __forceinline__ f16x4 cvt4(float4 v) {
    f16x4 h;
    h[0] = (_Float16)v.x; h[1] = (_Float16)v.y;
    h[2] = (_Float16)v.z; h[3] = (_Float16)v.w;
    return h;
}

// Kernel 1: inv text norms (reduce bit-identical to R1 — refine replicates R1
// fp32 values whose argmax matched np exactly, proven R3-R6) + optional fp16
// pre-scaled text, chunk-major+q-major: wsB slab(b,kc)[q:4][t:512][8 halfs].
// This is the exact linear LDS image for global_load_lds; frag reads at
// (q*512+t)*16B are 256-B contiguous per 16-lane group -> conflict-free.
template<bool PRE>
__global__ __launch_bounds__(256) void prep_text_kernel(const float* __restrict__ text,
                                                        float* __restrict__ inv_norm,
                                                        _Float16* __restrict__ wsB) {
    int row  = blockIdx.x * 4 + (threadIdx.x >> 6);
    int lane = threadIdx.x & 63;
    const float* p = text + (size_t)row * CD;
    float s = 0.f;
#pragma unroll
    for (int it = 0; it < 4; ++it) {
        int k = (lane + it * 64) * 4;
        float4 v = *reinterpret_cast<const float4*>(p + k);
        s = fmaf(v.x, v.x, s); s = fmaf(v.y, v.y, s);
        s = fmaf(v.z, v.z, s); s = fmaf(v.w, v.w, s);
    }
#pragma unroll
    for (int off = 32; off > 0; off >>= 1) s += __shfl_xor(s, off);
    float inv = 1.f / fmaxf(sqrtf(s), 1e-12f);
    if (lane == 0) inv_norm[row] = inv;

    if (PRE) {
        // lane owns k = lane*16 .. +15 -> chunk kc = lane>>1; q0 = (lane&1)*2
        int b = row >> 9, t = row & 511;
        int kc = lane >> 1;
        int q0 = (lane & 1) * 2;
        _Float16* slab = wsB + ((size_t)b * 32 + kc) * 16384;
        const float* src = p + lane * 16;
        f16x8 h0, h1;
#pragma unroll
        for (int j = 0; j < 2; ++j) {
            float4 v = *reinterpret_cast<const float4*>(src + j * 4);
            h0[j * 4 + 0] = (_Float16)(v.x * inv); h0[j * 4 + 1] = (_Float16)(v.y * inv);
            h0[j * 4 + 2] = (_Float16)(v.z * inv); h0[j * 4 + 3] = (_Float16)(v.w * inv);
        }
#pragma unroll
        for (int j = 0; j < 2; ++j) {
            float4 v = *reinterpret_cast<const float4*>(src + 8 + j * 4);
            h1[j * 4 + 0] = (_Float16)(v.x * inv); h1[j * 4 + 1] = (_Float16)(v.y * inv);
            h1[j * 4 + 2] = (_Float16)(v.z * inv); h1[j * 4 + 3] = (_Float16)(v.w * inv);
        }
        *reinterpret_cast<f16x8*>(slab + ((q0    ) * 512 + t) * 8) = h0;
        *reinterpret_cast<f16x8*>(slab + ((q0 + 1) * 512 + t) * 8) = h1;
    }
}

struct SmemM {
    _Float16 sB[2][4 * NT * 8];   // 65536 B : [buf][q*512+t][8 halfs]
    _Float16 sA[2][BM * BK];      //  8192 B : [buf][row][32 halfs, XOR-swizzled]
};
struct SmemE {
    float pval[8 * BM];
    int   pidx[8 * BM];
    float sval[BM];
    int   sidx[BM];
    int   rowcnt[BM];
    unsigned long long keys[BM];
    int   cand[MAXC];
    int   cnt;
};
union SmemU { SmemM m; SmemE e; };

// Kernel 2: fp16 MFMA sim-GEMM, one barrier per chunk, double-buffered LDS.
//   B: global_load_lds 1-KB contiguous from q-major wsB (WS=1) or reg-staged
//      fp32 text (WS=0 fallback)
//   A: coalesced 128-B-segment fp32 loads -> cvt -> swizzled ds_write
// 512 thr = 8 waves; wave w owns all 64 rows x 64-text slice.
// Epilogue (LDS union): approx argmax + candidate filter + exact fp32 refine
// + batched gather.
template<int WS>
__global__ __launch_bounds__(512, 4) void align_kernel(const float* __restrict__ img,
                                                       const float* __restrict__ text,
                                                       const float* __restrict__ inv_norm,
                                                       const _Float16* __restrict__ wsB,
                                                       float* __restrict__ out) {
    __shared__ SmemU sm;

    const int tid = threadIdx.x;
    const int l   = tid & 63;
    const int w   = tid >> 6;      // wave = 64-text slice (0..7)
    const int q   = l >> 4;        // quarter-wave -> k-slice q*8
    const int ln  = l & 15;

    const int b    = blockIdx.x & 7;
    const int row0 = (blockIdx.x >> 3) * BM;

    const float* imgBase  = img  + ((size_t)b * NI + row0) * CD;
    const float* textBase = text + (size_t)b * NT * CD;

    // A staging: thread -> (row = tid>>3, 16-B seg = tid&7); wave reads 8
    // contiguous 128-B row segments (coalesced).
    const int arow = tid >> 3, seg = tid & 7;
    const int aswz = (arow >> 1) & 3;                      // XOR swizzle key
    const int aOff = arow * 64 + ((seg * 8) ^ (aswz << 4)); // byte off in sA buf
    const float* aSrc = imgBase + (size_t)arow * CD + seg * 4;

    // B source slab for this batch (WS=1)
    const char* bSlab = (const char*)(wsB + (size_t)b * 32 * 16384);

    float invT = 0.f;
    if (!WS) invT = inv_norm[b * NT + tid];   // fallback: thread stages text row tid

    f32x4 acc[4][4];
#pragma unroll
    for (int mi = 0; mi < 4; ++mi)
#pragma unroll
        for (int nj = 0; nj < 4; ++nj) acc[mi][nj] = (f32x4)0.f;

    // ---- prologue: stage chunk 0 into buf 0 ----
    {
        if (WS) {
#pragma unroll
            for (int i = 0; i < 4; ++i)
                gl_lds16(bSlab + (w * 4 + i) * 1024 + l * 16,
                         (char*)&sm.m.sB[0][0] + (w * 4 + i) * 1024);
        } else {
            const float* bp = textBase + (size_t)tid * CD;
#pragma unroll
            for (int j = 0; j < 4; ++j) {
                float4 v0 = *reinterpret_cast<const float4*>(bp + j * 8);
                float4 v1 = *reinterpret_cast<const float4*>(bp + j * 8 + 4);
                f16x8 h;
                h[0] = (_Float16)(v0.x * invT); h[1] = (_Float16)(v0.y * invT);
                h[2] = (_Float16)(v0.z * invT); h[3] = (_Float16)(v0.w * invT);
                h[4] = (_Float16)(v1.x * invT); h[5] = (_Float16)(v1.y * invT);
                h[6] = (_Float16)(v1.z * invT); h[7] = (_Float16)(v1.w * invT);
                *reinterpret_cast<f16x8*>(&sm.m.sB[0][(j * 512 + tid) * 8]) = h;
            }
        }
        float4 v = *reinterpret_cast<const float4*>(aSrc);
        *reinterpret_cast<f16x4*>((char*)&sm.m.sA[0][0] + aOff) = cvt4(v);
    }
    __syncthreads();

    // ---- main loop: one barrier per chunk ----
    int buf = 0;
#pragma unroll 1
    for (int kc = 0; kc < NCH; ++kc) {
        const int nbuf = buf ^ 1;
        const bool more = (kc + 1 < NCH);
        float4 av;
        if (more) {
            av = *reinterpret_cast<const float4*>(aSrc + (kc + 1) * BK);
            if (WS) {
                const char* bs = bSlab + (size_t)(kc + 1) * 32768;
#pragma unroll
                for (int i = 0; i < 4; ++i)
                    gl_lds16(bs + (w * 4 + i) * 1024 + l * 16,
                             (char*)&sm.m.sB[nbuf][0] + (w * 4 + i) * 1024);
            }
        }

        // fragments (conflict-free reads) + 16 MFMA
        f16x8 af[4], bfv[4];
#pragma unroll
        for (int mi = 0; mi < 4; ++mi) {
            int row = mi * 16 + ln;
            af[mi] = *reinterpret_cast<const f16x8*>(
                (const char*)&sm.m.sA[buf][0] + row * 64 + ((q * 16) ^ (((row >> 1) & 3) << 4)));
        }
#pragma unroll
        for (int nj = 0; nj < 4; ++nj)
            bfv[nj] = *reinterpret_cast<const f16x8*>(
                &sm.m.sB[buf][(q * 512 + (w * 64 + nj * 16 + ln)) * 8]);
#pragma unroll
        for (int nj = 0; nj < 4; ++nj)
#pragma unroll
            for (int mi = 0; mi < 4; ++mi)
                acc[mi][nj] = __builtin_amdgcn_mfma_f32_16x16x32_f16(af[mi], bfv[nj], acc[mi][nj], 0, 0, 0);

        if (more) {
            if (!WS) {
                const float* bp = textBase + (size_t)tid * CD + (kc + 1) * BK;
#pragma unroll
                for (int j = 0; j < 4; ++j) {
                    float4 v0 = *reinterpret_cast<const float4*>(bp + j * 8);
                    float4 v1 = *reinterpret_cast<const float4*>(bp + j * 8 + 4);
                    f16x8 h;
                    h[0] = (_Float16)(v0.x * invT); h[1] = (_Float16)(v0.y * invT);
                    h[2] = (_Float16)(v0.z * invT); h[3] = (_Float16)(v0.w * invT);
                    h[4] = (_Float16)(v1.x * invT); h[5] = (_Float16)(v1.y * invT);
                    h[6] = (_Float16)(v1.z * invT); h[7] = (_Float16)(v1.w * invT);
                    *reinterpret_cast<f16x8*>(&sm.m.sB[nbuf][(j * 512 + tid) * 8]) = h;
                }
            }
            *reinterpret_cast<f16x4*>((char*)&sm.m.sA[nbuf][0] + aOff) = cvt4(av);
        }
        __syncthreads();
        buf = nbuf;
    }

    // ---- epilogue (LDS reused via union; all tile reads are done) ----
    // approx argmax per row with index (first-occurrence tie rule)
    // C/D layout: col = ln (text), row = q*4 + r  [m89]
#pragma unroll
    for (int mi = 0; mi < 4; ++mi) {
#pragma unroll
        for (int r = 0; r < 4; ++r) {
            float m  = acc[mi][0][r];
            int   bi = w * 64 + ln;
#pragma unroll
            for (int nj = 1; nj < 4; ++nj) {
                float v = acc[mi][nj][r];
                int  ci = w * 64 + nj * 16 + ln;
                if (v > m) { m = v; bi = ci; }
            }
#pragma unroll
            for (int off = 1; off < 16; off <<= 1) {
                float om = __shfl_xor(m, off);
                int   oi = __shfl_xor(bi, off);
                if (om > m || (om == m && oi < bi)) { m = om; bi = oi; }
            }
            if (ln == 0) {
                int rl = mi * 16 + q * 4 + r;
                sm.e.pval[w * BM + rl] = m;
                sm.e.pidx[w * BM + rl] = bi;
            }
        }
    }
    __syncthreads();

    // merge 8 slices (ascending w = ascending text -> first-occurrence holds)
    if (tid < BM) {
        float bv = sm.e.pval[tid];
        int   bi = sm.e.pidx[tid];
#pragma unroll
        for (int ww = 1; ww < 8; ++ww) {
            float v  = sm.e.pval[ww * BM + tid];
            int   i2 = sm.e.pidx[ww * BM + tid];
            if (v > bv || (v == bv && i2 < bi)) { bv = v; bi = i2; }
        }
        sm.e.sval[tid]   = bv;
        sm.e.sidx[tid]   = bi;    // exact answer if rowcnt==1
        sm.e.rowcnt[tid] = 0;
        sm.e.keys[tid]   = 0ull;
    }
    if (tid == 0) sm.e.cnt = 0;
    __syncthreads();

    // candidate collection: all (row,t) with approx >= rowmax - DELTA
    {
        float thr[4][4];
#pragma unroll
        for (int mi = 0; mi < 4; ++mi)
#pragma unroll
            for (int r = 0; r < 4; ++r)
                thr[mi][r] = sm.e.sval[mi * 16 + q * 4 + r] - DELTA;
#pragma unroll
        for (int mi = 0; mi < 4; ++mi)
#pragma unroll
            for (int nj = 0; nj < 4; ++nj)
#pragma unroll
                for (int r = 0; r < 4; ++r) {
                    if (acc[mi][nj][r] >= thr[mi][r]) {
                        int rl = mi * 16 + q * 4 + r;
                        int t  = w * 64 + nj * 16 + ln;
                        atomicAdd(&sm.e.rowcnt[rl], 1);
                        int slot = atomicAdd(&sm.e.cnt, 1);
                        if (slot < MAXC) sm.e.cand[slot] = (rl << 16) | t;
                    }
                }
    }
    __syncthreads();

    // exact fp32 refine, only rows with >=2 candidates (replicates R1
    // arithmetic exactly -> matches np argmax; proven R3-R6)
    {
        int n = sm.e.cnt < MAXC ? sm.e.cnt : MAXC;
        for (int c = tid; c < n; c += 512) {
            int rt = sm.e.cand[c];
            int rl = rt >> 16;
            int t  = rt & 0xFFFF;
            if (sm.e.rowcnt[rl] < 2) continue;
            const float* ap = imgBase  + (size_t)rl * CD;
            const float* bp = textBase + (size_t)t  * CD;
            float s = inv_norm[b * NT + t];
            float accv = 0.f;
#pragma unroll 2
            for (int k = 0; k < CD; k += 4) {
                float4 av = *reinterpret_cast<const float4*>(ap + k);
                float4 bv = *reinterpret_cast<const float4*>(bp + k);
                accv = fmaf(av.x, bv.x * s, accv);
                accv = fmaf(av.y, bv.y * s, accv);
                accv = fmaf(av.z, bv.z * s, accv);
                accv = fmaf(av.w, bv.w * s, accv);
            }
            unsigned ub = __float_as_uint(accv);
            unsigned su = ub ^ ((unsigned)((int)ub >> 31) | 0x80000000u);
            unsigned long long key =
                ((unsigned long long)su << 32) | (unsigned)(NT - 1 - t);
            atomicMax(&sm.e.keys[rl], key);
        }
    }
    __syncthreads();

    if (tid < BM && sm.e.rowcnt[tid] > 1)
        sm.e.sidx[tid] = NT - 1 - (int)(sm.e.keys[tid] & 0xFFFFFFFFull);
    __syncthreads();

    // gather: wave w copies rows w*8 .. w*8+7, batched 2 rows (8 loads in flight)
    float* outBase = out + ((size_t)b * NI + row0) * CD;
#pragma unroll 1
    for (int rr = 0; rr < 8; rr += 2) {
        int r0 = w * 8 + rr, r1 = r0 + 1;
        const float4* s0 = reinterpret_cast<const float4*>(textBase + (size_t)sm.e.sidx[r0] * CD);
        const float4* s1 = reinterpret_cast<const float4*>(textBase + (size_t)sm.e.sidx[r1] * CD);
        float4 v0[4], v1[4];
#pragma unroll
        for (int i = 0; i < 4; ++i) v0[i] = s0[l + 64 * i];
#pragma unroll
        for (int i = 0; i < 4; ++i) v1[i] = s1[l + 64 * i];
        float4* d0 = reinterpret_cast<float4*>(outBase + (size_t)r0 * CD);
        float4* d1 = reinterpret_cast<float4*>(outBase + (size_t)r1 * CD);
#pragma unroll
        for (int i = 0; i < 4; ++i) d0[l + 64 * i] = v0[i];
#pragma unroll
        for (int i = 0; i < 4; ++i) d1[l + 64 * i] = v1[i];
    }
}

extern "C" void kernel_launch(void* const* d_in, const int* in_sizes, int n_in,
                              void* d_out, int out_size, void* d_ws, size_t ws_size,
                              hipStream_t stream) {
    const float* img  = (const float*)d_in[0];   // [8,4096,1024] fp32
    const float* text = (const float*)d_in[1];   // [8,512,1024] fp32
    float* out      = (float*)d_out;             // [8,4096,1024] fp32
    float* inv_norm = (float*)d_ws;
    _Float16* wsB   = (_Float16*)((char*)d_ws + WS_NORM_B);

    const int gridAlign = NI / BM * B_;   // 512
    if (ws_size >= NEED_B) {
        prep_text_kernel<true><<<dim3(B_ * NT / 4), 256, 0, stream>>>(text, inv_norm, wsB);
        align_kernel<1><<<dim3(gridAlign), 512, 0, stream>>>(img, text, inv_norm, wsB, out);
    } else {
        prep_text_kernel<false><<<dim3(B_ * NT / 4), 256, 0, stream>>>(text, inv_norm, wsB);
        align_kernel<0><<<dim3(gridAlign), 512, 0, stream>>>(img, text, inv_norm, wsB, out);
    }
}